// Round 12
// baseline (89.219 us; speedup 1.0000x reference)
//
#include <hip/hip_runtime.h>

// Problem constants (match reference)
#define N_ 2048
#define D_ 16
#define O_ 3
#define S_ 10
#define E_ 4096
#define K_ 128

constexpr float STEP = 0.1f;            // (T_LAST - T_INIT) / S
constexpr int TILE = 128;
constexpr int T_ = N_ / TILE;           // 16 tile rows
constexpr int TP_ = T_ * (T_ + 1) / 2;  // 136 triangular tile pairs
constexpr int PAIR_BLOCKS = S_ * TP_;   // 1360
constexpr int EVENT_BLOCKS = E_ / 4;    // 1024 (4 events per block, 1 per wave)
constexpr int GRID = PAIR_BLOCKS + EVENT_BLOCKS; // 2384
constexpr float LOG2E = 1.4426950408889634f;

struct PairSm {
    // row stride = 9 float2 = 72 B: 8B-aligned ds_read_b64; with chunk
    // rotation ce=(cc+(tc>>1))&7 reads are <=2-way (free per m136) —
    // validated at R7: 0.70M conflict cycles.
    float2 xR[TILE][9];
    float2 xC[TILE][9];
    float sqR[TILE];
    float sqC[TILE];
    float gR[TILE];   // gamma * LOG2E
    float gC[TILE];
};
struct EvSm {
    float dz[4][O_][D_];   // four events per block (one per wave)
};

// 256 threads, 8x8 micro-tile: reads/FMA = 16/128 vs 4x8's 12/64 — 33%
// less LDS-pipe pressure at the SAME occupancy bin (65..128 VGPR -> 16
// waves/CU). NO min-waves hint: R7 showed __launch_bounds__(256,3) parks
// the accumulator in AGPRs (VGPR_Count=52 + accvgpr_read/write around
// every FMA, ~3x inner-loop VALU).
__global__ __launch_bounds__(256) void nhpp_main(
    const float* __restrict__ gamma,
    const float* __restrict__ z0,
    const float* __restrict__ et,
    const int* __restrict__ pairs,
    double* __restrict__ slots)      // [GRID], one per block, no atomics
{
    __shared__ union { PairSm p; EvSm ev; } sm;
    __shared__ float wred[4];

    const int tid = threadIdx.x;
    const int bid = blockIdx.x;

    if (bid < PAIR_BLOCKS) {
        // ---------------- pairwise integral path ----------------
        const int s = bid / TP_;
        int rem = bid % TP_;
        int ti = 0;
        while (rem >= T_ - ti) { rem -= T_ - ti; ++ti; }
        const int tj = ti + rem;
        const bool diag = (ti == tj);

        const float t  = STEP * (float)s;
        const float c1 = t;
        const float c2 = 0.5f * t * t;

        // stage both x tiles: 2 tiles * 128 rows * 8 float2-chunks = 2048
        // float2 -> 8 iterations of 256 threads; coalesced float2 loads.
        #pragma unroll
        for (int it = 0; it < 8; ++it) {
            const int e4 = it * 256 + tid;
            const int r  = (e4 >> 3) & 127;
            const int ch = e4 & 7;
            const int n  = ((it < 4) ? ti : tj) * TILE + r;
            const float* p0 = z0 + (0 * N_ + n) * D_ + 2 * ch;
            const float2 v0 = *(const float2*)(p0);
            const float2 v1 = *(const float2*)(p0 + N_ * D_);
            const float2 v2 = *(const float2*)(p0 + 2 * N_ * D_);
            float2 x;
            x.x = fmaf(c2, v2.x, fmaf(c1, v1.x, v0.x));
            x.y = fmaf(c2, v2.y, fmaf(c1, v1.y, v0.y));
            if (it < 4) sm.p.xR[r][ch] = x;
            else        sm.p.xC[r][ch] = x;
        }
        __syncthreads();

        // per-row |x|^2 and gamma*LOG2E
        {
            const int r = tid & 127;
            const float2* row = (tid < 128) ? sm.p.xR[r] : sm.p.xC[r];
            float ssq = 0.f;
            #pragma unroll
            for (int ch = 0; ch < 8; ++ch) {
                const float2 v = row[ch];
                ssq = fmaf(v.x, v.x, fmaf(v.y, v.y, ssq));
            }
            const int n = ((tid < 128) ? ti : tj) * TILE + r;
            const float gl = gamma[n] * LOG2E;
            if (tid < 128) { sm.p.sqR[r] = ssq; sm.p.gR[r] = gl; }
            else           { sm.p.sqC[r] = ssq; sm.p.gC[r] = gl; }
        }
        __syncthreads();

        // 8x8 register micro-tile over a 128x128 tile (16 x 16 threads).
        const int tr = tid >> 4;    // 0..15
        const int tc = tid & 15;    // 0..15
        const int r0 = tr * 8, c0 = tc * 8;
        const int rot = (tc >> 1) & 7;

        float a8[8][8];
        #pragma unroll
        for (int i = 0; i < 8; ++i)
            #pragma unroll
            for (int j = 0; j < 8; ++j) a8[i][j] = 0.f;

        #pragma unroll
        for (int cc = 0; cc < 8; ++cc) {
            const int ce = (cc + rot) & 7;
            float2 xr[8], xc[8];
            #pragma unroll
            for (int i = 0; i < 8; ++i) xr[i] = sm.p.xR[r0 + i][ce];
            #pragma unroll
            for (int j = 0; j < 8; ++j) xc[j] = sm.p.xC[c0 + j][ce];
            #pragma unroll
            for (int i = 0; i < 8; ++i)
                #pragma unroll
                for (int j = 0; j < 8; ++j)
                    a8[i][j] = fmaf(xr[i].x, xc[j].x,
                               fmaf(xr[i].y, xc[j].y, a8[i][j]));
        }

        float sqr[8], grl[8];
        #pragma unroll
        for (int i = 0; i < 8; ++i) {
            sqr[i] = sm.p.sqR[r0 + i];
            grl[i] = sm.p.gR[r0 + i];
        }

        float ls0 = 0.f, ls1 = 0.f;
        #pragma unroll
        for (int j = 0; j < 8; ++j) {
            const float sqc = sm.p.sqC[c0 + j];
            const float gcl = sm.p.gC[c0 + j];
            #pragma unroll
            for (int i = 0; i < 8; ++i) {
                const float d2   = fmaf(-2.0f, a8[i][j], sqr[i] + sqc);
                const float dist = sqrtf(fmaxf(d2, 0.0f));
                float v = exp2f(fmaf(-LOG2E, dist, grl[i] + gcl));
                if (diag) v = (r0 + i < c0 + j) ? v : 0.f;
                if (i & 1) ls1 += v; else ls0 += v;
            }
        }
        float lsum = ls0 + ls1;

        #pragma unroll
        for (int off = 32; off; off >>= 1) lsum += __shfl_down(lsum, off, 64);
        if ((tid & 63) == 0) wred[tid >> 6] = lsum;
        __syncthreads();
        if (tid == 0) {
            const float b = wred[0] + wred[1] + wred[2] + wred[3];
            slots[bid] = (double)(b * STEP);
        }
    } else {
        // ---------------- event log-intensity path ----------------
        const int bb   = bid - PAIR_BLOCKS;
        const int w    = tid >> 6;       // wave = event slot (0..3)
        const int lane = tid & 63;
        const int e    = bb * 4 + w;
        const int pi   = pairs[2 * e + 0];
        const int pj   = pairs[2 * e + 1];

        if (lane < O_ * D_) {
            const int o = lane >> 4, d = lane & 15;
            const float inv = (o == 2) ? 0.5f : 1.0f;   // 1/fact
            sm.ev.dz[w][o][d] =
                (z0[(o * N_ + pi) * D_ + d] - z0[(o * N_ + pj) * D_ + d]) * inv;
        }
        __syncthreads();

        const float2 tt = *(const float2*)(et + e * K_ + 2 * lane);
        float ed = 0.f;
        #pragma unroll
        for (int h = 0; h < 2; ++h) {
            const float tk = (h == 0) ? tt.x : tt.y;
            float ss = 0.f;
            #pragma unroll
            for (int d = 0; d < D_; ++d) {
                const float v = fmaf(tk, fmaf(tk, sm.ev.dz[w][2][d],
                                              sm.ev.dz[w][1][d]),
                                     sm.ev.dz[w][0][d]);
                ss = fmaf(v, v, ss);
            }
            ed += sqrtf(fmaxf(ss, 0.0f));
        }
        #pragma unroll
        for (int off = 32; off; off >>= 1) ed += __shfl_down(ed, off, 64);
        if (lane == 0)
            wred[w] = ed - (float)K_ * (gamma[pi] + gamma[pj]); // = -log_int
        __syncthreads();
        if (tid == 0) {
            const float b = wred[0] + wred[1] + wred[2] + wred[3];
            slots[bid] = (double)b;
        }
    }
}

// Final reduction over per-block partials — separate dispatch, so no
// atomic counter / memset needed (every slot is written unconditionally
// by its block; harness poison is always overwritten).
__global__ __launch_bounds__(512) void nhpp_reduce(
    const double* __restrict__ slots, float* __restrict__ out)
{
    __shared__ double w8[8];
    const int tid = threadIdx.x;
    double s = 0.0;
    for (int i = tid; i < GRID; i += 512) s += slots[i];
    #pragma unroll
    for (int off = 32; off; off >>= 1) s += __shfl_down(s, off, 64);
    if ((tid & 63) == 0) w8[tid >> 6] = s;
    __syncthreads();
    if (tid == 0) {
        double t = 0.0;
        #pragma unroll
        for (int k = 0; k < 8; ++k) t += w8[k];
        out[0] = (float)t;
    }
}

extern "C" void kernel_launch(void* const* d_in, const int* in_sizes, int n_in,
                              void* d_out, int out_size, void* d_ws, size_t ws_size,
                              hipStream_t stream) {
    (void)in_sizes; (void)n_in; (void)out_size; (void)ws_size;
    const float* gamma = (const float*)d_in[0];
    const float* z0    = (const float*)d_in[1];
    const float* et    = (const float*)d_in[2];
    const int*   pairs = (const int*)d_in[3];
    float* out = (float*)d_out;

    double* slots = (double*)d_ws;   // GRID * 8 B = 19 KB

    nhpp_main<<<GRID, 256, 0, stream>>>(gamma, z0, et, pairs, slots);
    nhpp_reduce<<<1, 512, 0, stream>>>(slots, out);
}